// Round 3
// baseline (1648.691 us; speedup 1.0000x reference)
//
#include <hip/hip_runtime.h>

typedef unsigned short u16;
typedef float f32x4 __attribute__((ext_vector_type(4)));
typedef __bf16 bf16x8 __attribute__((ext_vector_type(8)));

#define T_ 8
#define B_ 16
#define C_ 384
#define N_ 1024
#define HEADS_ 8
#define HD_ 48
#define NC_ 4
#define EPS_ 1e-5f
#define SCALE_ (1.0f / 32.0f)

__device__ __forceinline__ float bf2f(u16 u) {
  union { unsigned int i; float f; } x;
  x.i = ((unsigned int)u) << 16;
  return x.f;
}
__device__ __forceinline__ u16 f2bf(float f) {
  unsigned int u = __float_as_uint(f);
  u += 0x7fffu + ((u >> 16) & 1u);
  return (u16)(u >> 16);
}

// ---------------------------------------------------------------------------
// Kernel 1: q/k/v projections. Inputs f32; tiles converted to bf16 in LDS.
// Per (t,b): Y[o,n] = sum_c W[o,c]*relu(X[c,n]), then BN + ReLU.
// q,k stored bf16 [T,B,C,N]; v stored f32 heads-layout [T,B,H,N,HD] (output 1)
// via the transposed MFMA orientation (D rows = n, cols = o).
// ---------------------------------------------------------------------------
__global__ __launch_bounds__(256) void qkv_gemm(
    const float* __restrict__ x,
    const float* __restrict__ wq, const float* __restrict__ bnq,
    const float* __restrict__ wk, const float* __restrict__ bnk,
    const float* __restrict__ wv, const float* __restrict__ bnv,
    u16* __restrict__ qo, u16* __restrict__ ko, float* __restrict__ vo) {
  const int tb = blockIdx.z / 3;
  const int pr = blockIdx.z % 3;
  const float* wm = (pr == 0) ? wq : (pr == 1) ? wk : wv;
  const float* bn = (pr == 0) ? bnq : (pr == 1) ? bnk : bnv;
  const int n0 = blockIdx.x * 64;
  const int o0 = blockIdx.y * 64;
  const float* xb = x + (size_t)tb * C_ * N_;

  __shared__ u16 Ws[64][40];   // rows = o, cols = c (contiguous k for frags)
  __shared__ u16 Xst[64][40];  // rows = n, cols = c (transposed X tile)

  const int tid = threadIdx.x;
  const int lane = tid & 63;
  const int wave = tid >> 6;
  const int wr = wave >> 1, wc = wave & 1;
  const int qd = lane >> 4, l15 = lane & 15;

  const int ar = tid >> 2, ac = (tid & 3) << 3;  // W stage: 64 o x 32 c
  const int br = tid >> 3, bc = (tid & 7) << 3;  // X stage: 32 c x 64 n

  f32x4 acc[2][2];
#pragma unroll
  for (int i = 0; i < 2; ++i)
#pragma unroll
    for (int j = 0; j < 2; ++j) acc[i][j] = (f32x4){0.f, 0.f, 0.f, 0.f};

  for (int c0 = 0; c0 < C_; c0 += 32) {
    float4 a0 = *(const float4*)(wm + (size_t)(o0 + ar) * C_ + c0 + ac);
    float4 a1 = *(const float4*)(wm + (size_t)(o0 + ar) * C_ + c0 + ac + 4);
    float4 b0 = *(const float4*)(xb + (size_t)(c0 + br) * N_ + n0 + bc);
    float4 b1 = *(const float4*)(xb + (size_t)(c0 + br) * N_ + n0 + bc + 4);
    __syncthreads();
    u16 tmp[8];
    tmp[0] = f2bf(a0.x); tmp[1] = f2bf(a0.y);
    tmp[2] = f2bf(a0.z); tmp[3] = f2bf(a0.w);
    tmp[4] = f2bf(a1.x); tmp[5] = f2bf(a1.y);
    tmp[6] = f2bf(a1.z); tmp[7] = f2bf(a1.w);
    *(uint4*)(&Ws[ar][ac]) = *(const uint4*)tmp;
    float bv[8] = {b0.x, b0.y, b0.z, b0.w, b1.x, b1.y, b1.z, b1.w};
#pragma unroll
    for (int j = 0; j < 8; ++j)
      Xst[bc + j][br] = f2bf(fmaxf(bv[j], 0.f));  // relu(x)
    __syncthreads();
    const u16(*Ar)[40] = (pr == 2) ? Xst : Ws;
    const u16(*Br)[40] = (pr == 2) ? Ws : Xst;
    bf16x8 af[2], bfv[2];
#pragma unroll
    for (int mi = 0; mi < 2; ++mi)
      af[mi] = *(const bf16x8*)(&Ar[wr * 32 + mi * 16 + l15][qd * 8]);
#pragma unroll
    for (int ni = 0; ni < 2; ++ni)
      bfv[ni] = *(const bf16x8*)(&Br[wc * 32 + ni * 16 + l15][qd * 8]);
#pragma unroll
    for (int mi = 0; mi < 2; ++mi)
#pragma unroll
      for (int ni = 0; ni < 2; ++ni)
        acc[mi][ni] = __builtin_amdgcn_mfma_f32_16x16x32_bf16(
            af[mi], bfv[ni], acc[mi][ni], 0, 0, 0);
  }

  if (pr < 2) {
    // D rows = o, cols = n -> write bf16 [T,B,C,N]
    u16* out = (pr == 0) ? qo : ko;
#pragma unroll
    for (int mi = 0; mi < 2; ++mi) {
#pragma unroll
      for (int r = 0; r < 4; ++r) {
        int o = o0 + wr * 32 + mi * 16 + qd * 4 + r;
        float g = bn[o], be = bn[C_ + o];
        float mu = bn[2 * C_ + o], va = bn[3 * C_ + o];
        float inv = g * rsqrtf(va + EPS_);
        float sh = be - mu * inv;
        size_t rowbase = ((size_t)tb * C_ + o) * N_;
#pragma unroll
        for (int ni = 0; ni < 2; ++ni) {
          int n = n0 + wc * 32 + ni * 16 + l15;
          float val = fmaxf(acc[mi][ni][r] * inv + sh, 0.f);
          out[rowbase + n] = f2bf(val);
        }
      }
    }
  } else {
    // transposed orientation: D rows = n, cols = o -> f32 heads layout write
#pragma unroll
    for (int ni = 0; ni < 2; ++ni) {
      int o = o0 + wc * 32 + ni * 16 + l15;
      float g = bn[o], be = bn[C_ + o];
      float mu = bn[2 * C_ + o], va = bn[3 * C_ + o];
      float inv = g * rsqrtf(va + EPS_);
      float sh = be - mu * inv;
      int hh = o / HD_, dd = o % HD_;
      size_t base = (((size_t)tb * HEADS_ + hh) * N_) * HD_ + dd;
#pragma unroll
      for (int mi = 0; mi < 2; ++mi)
#pragma unroll
        for (int r = 0; r < 4; ++r) {
          int n = n0 + wr * 32 + mi * 16 + qd * 4 + r;
          float val = fmaxf(acc[mi][ni][r] * inv + sh, 0.f);
          vo[base + (size_t)n * HD_] = val;
        }
    }
  }
}

// ---------------------------------------------------------------------------
// Kernel 2: attn[g,d,e] = (1/32) * sum_s k[g,s,d] * v[g,s,e], S = 2*1024.
// k bf16 [T,B,C,N]; v f32 heads layout [T,B,H,N,HD]. attn fp32.
// ---------------------------------------------------------------------------
__global__ __launch_bounds__(256) void attn_kv(const u16* __restrict__ kk,
                                               const float* __restrict__ vv,
                                               float* __restrict__ attn) {
  const int g = blockIdx.x;  // (cI*B + b)*HEADS + h
  const int h = g % HEADS_;
  const int b = (g / HEADS_) % B_;
  const int cI = g / (HEADS_ * B_);
  const int tid = threadIdx.x;
  const int te = tid & 15, td = tid >> 4;

  __shared__ u16 ks[48][72];
  __shared__ float vsf[64 * 48];

  float acc[3][3];
#pragma unroll
  for (int i = 0; i < 3; ++i)
#pragma unroll
    for (int j = 0; j < 3; ++j) acc[i][j] = 0.f;

  for (int tc = 0; tc < 2; ++tc) {
    int t = cI * 2 + tc;
    size_t kbase = ((size_t)(t * B_ + b) * C_ + h * HD_) * N_;
    size_t vbase = ((size_t)(t * B_ + b) * HEADS_ + h) * N_ * HD_;
    for (int n0 = 0; n0 < N_; n0 += 64) {
      __syncthreads();
      for (int idx = tid; idx < 48 * 64; idx += 256) {
        int d = idx >> 6, j = idx & 63;
        ks[d][j] = kk[kbase + (size_t)d * N_ + n0 + j];
      }
      for (int idx = tid; idx < 64 * 48; idx += 256)
        vsf[idx] = vv[vbase + (size_t)n0 * HD_ + idx];
      __syncthreads();
      for (int n = 0; n < 64; ++n) {
        float kf[3], vf[3];
#pragma unroll
        for (int i = 0; i < 3; ++i) kf[i] = bf2f(ks[td + 16 * i][n]);
#pragma unroll
        for (int i = 0; i < 3; ++i) vf[i] = vsf[n * 48 + te + 16 * i];
#pragma unroll
        for (int i = 0; i < 3; ++i)
#pragma unroll
          for (int j = 0; j < 3; ++j) acc[i][j] += kf[i] * vf[j];
      }
    }
  }
#pragma unroll
  for (int i = 0; i < 3; ++i)
#pragma unroll
    for (int j = 0; j < 3; ++j)
      attn[((size_t)g * 48 + td + 16 * i) * 48 + te + 16 * j] =
          acc[i][j] * SCALE_;
}

// ---------------------------------------------------------------------------
// Kernel 3: out[t,b,h*48+e,n] = relu( sum_d q[t,b,h*48+d,n] * attn[g,d,e] )
// q bf16, ao bf16.
// ---------------------------------------------------------------------------
__global__ __launch_bounds__(256) void q_attn(const u16* __restrict__ qq,
                                              const float* __restrict__ attn,
                                              u16* __restrict__ ao) {
  const int n0 = blockIdx.x * 64;
  const int z = blockIdx.y;  // t*B*HEADS + b*HEADS + h
  const int h = z % HEADS_;
  const int b = (z / HEADS_) % B_;
  const int t = z / (HEADS_ * B_);
  const int cI = t / 2;
  const int g = (cI * B_ + b) * HEADS_ + h;
  const int tid = threadIdx.x;
  const int nl = tid & 63, eg = tid >> 6, e0 = eg * 12;

  __shared__ float at[48 * 48];
  for (int idx = tid; idx < 48 * 48; idx += 256)
    at[idx] = attn[(size_t)g * 2304 + idx];
  __syncthreads();

  size_t qbase = ((size_t)(t * B_ + b) * C_ + h * HD_) * N_ + n0 + nl;
  float acc[12];
#pragma unroll
  for (int j = 0; j < 12; ++j) acc[j] = 0.f;
  for (int d = 0; d < 48; ++d) {
    float qv = bf2f(qq[qbase + (size_t)d * N_]);
#pragma unroll
    for (int j = 0; j < 12; ++j) acc[j] += qv * at[d * 48 + e0 + j];
  }
  size_t obase = ((size_t)(t * B_ + b) * C_ + h * HD_) * N_ + n0 + nl;
#pragma unroll
  for (int j = 0; j < 12; ++j)
    ao[obase + (size_t)(e0 + j) * N_] = f2bf(fmaxf(acc[j], 0.f));
}

// ---------------------------------------------------------------------------
// Kernel 4: proj GEMM + bias + BN + residual. y = bn(P*ao + pb) + x
// ao bf16; P, pb, bn, x f32; y f32 (output 0).
// ---------------------------------------------------------------------------
__global__ __launch_bounds__(256) void proj_gemm(
    const u16* __restrict__ ao, const float* __restrict__ pw,
    const float* __restrict__ pb, const float* __restrict__ pbn,
    const float* __restrict__ x, float* __restrict__ y) {
  const int tb = blockIdx.z;
  const int n0 = blockIdx.x * 64;
  const int o0 = blockIdx.y * 64;
  const u16* ab = ao + (size_t)tb * C_ * N_;

  __shared__ u16 Ws[64][40];
  __shared__ u16 Xst[64][40];

  const int tid = threadIdx.x;
  const int lane = tid & 63;
  const int wave = tid >> 6;
  const int wr = wave >> 1, wc = wave & 1;
  const int qd = lane >> 4, l15 = lane & 15;

  const int ar = tid >> 2, ac = (tid & 3) << 3;
  const int br = tid >> 3, bc = (tid & 7) << 3;

  f32x4 acc[2][2];
#pragma unroll
  for (int i = 0; i < 2; ++i)
#pragma unroll
    for (int j = 0; j < 2; ++j) acc[i][j] = (f32x4){0.f, 0.f, 0.f, 0.f};

  for (int c0 = 0; c0 < C_; c0 += 32) {
    float4 a0 = *(const float4*)(pw + (size_t)(o0 + ar) * C_ + c0 + ac);
    float4 a1 = *(const float4*)(pw + (size_t)(o0 + ar) * C_ + c0 + ac + 4);
    uint4 bx = *(const uint4*)(ab + (size_t)(c0 + br) * N_ + n0 + bc);
    __syncthreads();
    u16 tmp[8];
    tmp[0] = f2bf(a0.x); tmp[1] = f2bf(a0.y);
    tmp[2] = f2bf(a0.z); tmp[3] = f2bf(a0.w);
    tmp[4] = f2bf(a1.x); tmp[5] = f2bf(a1.y);
    tmp[6] = f2bf(a1.z); tmp[7] = f2bf(a1.w);
    *(uint4*)(&Ws[ar][ac]) = *(const uint4*)tmp;
    const u16* hp = (const u16*)&bx;
#pragma unroll
    for (int j = 0; j < 8; ++j) Xst[bc + j][br] = hp[j];  // ao already bf16
    __syncthreads();
    bf16x8 af[2], bfv[2];
#pragma unroll
    for (int mi = 0; mi < 2; ++mi)
      af[mi] = *(const bf16x8*)(&Ws[wr * 32 + mi * 16 + l15][qd * 8]);
#pragma unroll
    for (int ni = 0; ni < 2; ++ni)
      bfv[ni] = *(const bf16x8*)(&Xst[wc * 32 + ni * 16 + l15][qd * 8]);
#pragma unroll
    for (int mi = 0; mi < 2; ++mi)
#pragma unroll
      for (int ni = 0; ni < 2; ++ni)
        acc[mi][ni] = __builtin_amdgcn_mfma_f32_16x16x32_bf16(
            af[mi], bfv[ni], acc[mi][ni], 0, 0, 0);
  }

#pragma unroll
  for (int mi = 0; mi < 2; ++mi) {
#pragma unroll
    for (int r = 0; r < 4; ++r) {
      int o = o0 + wr * 32 + mi * 16 + qd * 4 + r;
      float g = pbn[o], be = pbn[C_ + o];
      float mu = pbn[2 * C_ + o], va = pbn[3 * C_ + o];
      float inv = g * rsqrtf(va + EPS_);
      float add = pb[o] * inv + (be - mu * inv);
      size_t rowbase = ((size_t)tb * C_ + o) * N_;
#pragma unroll
      for (int ni = 0; ni < 2; ++ni) {
        int n = n0 + wc * 32 + ni * 16 + l15;
        float val = acc[mi][ni][r] * inv + add;
        val += x[rowbase + n];  // residual (pre-relu x)
        y[rowbase + n] = val;
      }
    }
  }
}

extern "C" void kernel_launch(void* const* d_in, const int* in_sizes, int n_in,
                              void* d_out, int out_size, void* d_ws,
                              size_t ws_size, hipStream_t stream) {
  const float* x = (const float*)d_in[0];
  const float* q_w = (const float*)d_in[1];
  const float* q_bn = (const float*)d_in[2];
  const float* k_w = (const float*)d_in[3];
  const float* k_bn = (const float*)d_in[4];
  const float* v_w = (const float*)d_in[5];
  const float* v_bn = (const float*)d_in[6];
  const float* p_w = (const float*)d_in[7];
  const float* p_b = (const float*)d_in[8];
  const float* p_bn = (const float*)d_in[9];

  const size_t NELEM = (size_t)T_ * B_ * C_ * N_;  // 50,331,648
  float* y_out = (float*)d_out;          // output 0: y, f32
  float* v_out = y_out + NELEM;          // output 1: v, f32 heads layout

  // q (bf16, 2*NELEM bytes) lives in the y region (4*NELEM bytes), which is
  // dead until proj_gemm; q is dead before proj_gemm runs.
  u16* q_ws = (u16*)y_out;
  u16* k_ws = (u16*)d_ws;
  float* attn_ws = (float*)(k_ws + NELEM);
  u16* ao_ws = k_ws;  // k dead after attn_kv; reuse for attention output

  qkv_gemm<<<dim3(16, 6, T_ * B_ * 3), 256, 0, stream>>>(
      x, q_w, q_bn, k_w, k_bn, v_w, v_bn, q_ws, k_ws, v_out);
  attn_kv<<<dim3(NC_ * B_ * HEADS_), 256, 0, stream>>>(k_ws, v_out, attn_ws);
  q_attn<<<dim3(16, T_ * B_ * HEADS_), 256, 0, stream>>>(q_ws, attn_ws, ao_ws);
  proj_gemm<<<dim3(16, 6, T_ * B_), 256, 0, stream>>>(ao_ws, p_w, p_b, p_bn, x,
                                                      y_out);
}